// Round 13
// baseline (485.575 us; speedup 1.0000x reference)
//
#include <hip/hip_runtime.h>
#include <hip/hip_bf16.h>
#include <math.h>

// Problem constants (from reference)
constexpr int Bb  = 8;
constexpr int Tt  = 1024;
constexpr int CIN = 6;
constexpr int Dd  = 128;
constexpr int Ll  = 2;
constexpr int DI  = 256;
constexpr int DS  = 32;
constexpr int DC  = 4;
constexpr int DTR = 8;
constexpr int NX  = DTR + 2 * DS;   // 72
constexpr int ROWS = Bb * Tt;       // 8192

using u16 = unsigned short;
using u32 = unsigned int;

typedef __attribute__((ext_vector_type(8))) short short8b;  // 8 bf16 (4 VGPR)
typedef __attribute__((ext_vector_type(4))) float f32x4;

__device__ __forceinline__ float f4c(const float4& v, int k) {
  return k == 0 ? v.x : k == 1 ? v.y : k == 2 ? v.z : v.w;
}

// f32 -> bf16 (RNE), raw bits
__device__ __forceinline__ u16 f2bf(float f) {
  u32 x = __float_as_uint(f);
  u32 r = (x + 0x7fffu + ((x >> 16) & 1u)) >> 16;
  return (u16)r;
}
__device__ __forceinline__ u32 pack2bf(float lo, float hi) {
  return (u32)f2bf(lo) | ((u32)f2bf(hi) << 16);
}

// VALU (DPP) lane-sum stage: x + dpp_move(x). Avoids the DS pipe entirely.
template <int CTRL, int ROW_MASK>
__device__ __forceinline__ float dpp_add(float x) {
  int m = __builtin_amdgcn_update_dpp(0, __float_as_int(x), CTRL, ROW_MASK, 0xF, true);
  return x + __int_as_float(m);
}
// Sum of 32 lanes within each 32-lane half-wave; result in lane s==31 (and 63).
__device__ __forceinline__ float half_wave_sum31(float p) {
  p = dpp_add<0x111, 0xF>(p);
  p = dpp_add<0x112, 0xF>(p);
  p = dpp_add<0x114, 0xF>(p);
  p = dpp_add<0x118, 0xF>(p);
  p = dpp_add<0x142, 0xA>(p);
  return p;
}

// ---------------------------------------------------------------------------
// Frontend: Conv1d(CIN->D, k=3, pad=1) + BN(eval) + ReLU
// ---------------------------------------------------------------------------
__global__ __launch_bounds__(128) void frontend_k(
    const float* __restrict__ x, const float* __restrict__ fw,
    const float* __restrict__ fb, const float* __restrict__ g,
    const float* __restrict__ bnb, float* __restrict__ h) {
  int t = blockIdx.x, b = blockIdx.y, d = threadIdx.x;
  float acc = 0.f;
#pragma unroll
  for (int k = 0; k < 3; ++k) {
    int tt = t - 1 + k;
    if (tt < 0 || tt >= Tt) continue;
    const float* xp = x + ((size_t)b * Tt + tt) * CIN;
#pragma unroll
    for (int c = 0; c < CIN; ++c)
      acc = fmaf(xp[c], fw[(d * CIN + c) * 3 + k], acc);
  }
  float scale = g[d] * rsqrtf(1.f + 1e-5f);
  float val = scale * (acc + fb[d]) + bnb[d];
  h[((size_t)b * Tt + t) * Dd + d] = fmaxf(val, 0.f);
}

// ---------------------------------------------------------------------------
// RMSNorm (final only). One wave per row; 4 rows/block.
// ---------------------------------------------------------------------------
__global__ __launch_bounds__(256) void rms_k(const float* __restrict__ in,
                                             const float* __restrict__ w,
                                             float* __restrict__ out) {
  int lane = threadIdx.x & 63;
  int row  = blockIdx.x * 4 + (threadIdx.x >> 6);
  const float* p = in + (size_t)row * Dd;
  float x0 = p[lane], x1 = p[lane + 64];
  float ss = fmaf(x0, x0, x1 * x1);
#pragma unroll
  for (int m = 1; m < 64; m <<= 1) ss += __shfl_xor(ss, m);
  float rs = rsqrtf(ss * (1.f / Dd) + 1e-6f);
  out[(size_t)row * Dd + lane]      = x0 * w[lane] * rs;
  out[(size_t)row * Dd + lane + 64] = x1 * w[lane + 64] * rs;
}

// ---------------------------------------------------------------------------
// f32 tiled GEMM (kept for W_xproj, N=72 tail): C = A @ W (+C if ADD_C)
// ---------------------------------------------------------------------------
template <bool ADD_C>
__global__ __launch_bounds__(256) void sgemm_k(const float* __restrict__ A,
                                               const float* __restrict__ W,
                                               float* __restrict__ C,
                                               int M, int N, int K) {
  constexpr int BM = 128, BN = 64, BK = 32;
  __shared__ float As[BK][BM + 1];
  __shared__ float Ws[BK][BN];
  int tid = threadIdx.x;
  int tx = tid & 15, ty = tid >> 4;
  int bm = blockIdx.x * BM, bn = blockIdx.y * BN;
  float acc[8][4] = {};
  for (int k0 = 0; k0 < K; k0 += BK) {
#pragma unroll
    for (int i = 0; i < 4; ++i) {
      int qi = tid + i * 256;
      int r = qi >> 3, kq = (qi & 7) * 4;
      const float4 av = *(const float4*)(A + (size_t)(bm + r) * K + k0 + kq);
      As[kq + 0][r] = av.x; As[kq + 1][r] = av.y;
      As[kq + 2][r] = av.z; As[kq + 3][r] = av.w;
    }
#pragma unroll
    for (int i = 0; i < 2; ++i) {
      int qi = tid + i * 256;
      int kr = qi >> 4, nq = (qi & 15) * 4;
      int gn = bn + nq;
      float4 wv;
      if (gn + 3 < N) {
        wv = *(const float4*)(W + (size_t)(k0 + kr) * N + gn);
      } else {
        wv.x = (gn + 0 < N) ? W[(size_t)(k0 + kr) * N + gn + 0] : 0.f;
        wv.y = (gn + 1 < N) ? W[(size_t)(k0 + kr) * N + gn + 1] : 0.f;
        wv.z = (gn + 2 < N) ? W[(size_t)(k0 + kr) * N + gn + 2] : 0.f;
        wv.w = (gn + 3 < N) ? W[(size_t)(k0 + kr) * N + gn + 3] : 0.f;
      }
      *(float4*)&Ws[kr][nq] = wv;
    }
    __syncthreads();
#pragma unroll
    for (int kk = 0; kk < BK; ++kk) {
      float av[8], wv[4];
#pragma unroll
      for (int i = 0; i < 8; ++i) av[i] = As[kk][ty * 8 + i];
#pragma unroll
      for (int j = 0; j < 4; ++j) wv[j] = Ws[kk][tx * 4 + j];
#pragma unroll
      for (int i = 0; i < 8; ++i)
#pragma unroll
        for (int j = 0; j < 4; ++j)
          acc[i][j] = fmaf(av[i], wv[j], acc[i][j]);
    }
    __syncthreads();
  }
#pragma unroll
  for (int i = 0; i < 8; ++i) {
    int r = bm + ty * 8 + i;
#pragma unroll
    for (int j = 0; j < 4; ++j) {
      int c = bn + tx * 4 + j;
      if (c < N) {
        size_t off = (size_t)r * N + c;
        C[off] = acc[i][j] + (ADD_C ? C[off] : 0.f);
      }
    }
  }
}

// ---------------------------------------------------------------------------
// wtrans_k: W[K][N] f32 -> Wt[N][K] bf16 (transpose + cast), 32x32 LDS tiles.
// grid (K/32, N/32, L); layer stride = K*N on both.
// ---------------------------------------------------------------------------
__global__ __launch_bounds__(256) void wtrans_k(const float* __restrict__ W,
                                                u16* __restrict__ Wt,
                                                int K, int N) {
  __shared__ float tile[32][33];
  int k0 = blockIdx.x * 32, n0 = blockIdx.y * 32;
  size_t lofs = (size_t)blockIdx.z * K * N;
  const float* Wp = W + lofs;
  u16* Wtp = Wt + lofs;
  int j = threadIdx.x & 31, i0 = threadIdx.x >> 5;
#pragma unroll
  for (int ii = 0; ii < 4; ++ii) {
    int k = i0 + ii * 8;
    tile[k][j] = Wp[(size_t)(k0 + k) * N + n0 + j];
  }
  __syncthreads();
  int kp = (threadIdx.x & 15) * 2;
  int nb = threadIdx.x >> 4;  // 0..15
#pragma unroll
  for (int half = 0; half < 2; ++half) {
    int n = nb + half * 16;
    u32 u = (u32)f2bf(tile[kp][n]) | ((u32)f2bf(tile[kp + 1][n]) << 16);
    *(u32*)&Wtp[(size_t)(n0 + n) * K + k0 + kp] = u;
  }
}

// ---------------------------------------------------------------------------
// bgemm_rms_k: fused RMSNorm + bf16-MFMA GEMM for W_in.
// C[M,512] = rmsnorm(A[M,128], w) @ W_in  (Wt = pre-transposed bf16 [N][K]).
// K=128 fixed: entire K staged once (no k-loop barriers). 4 waves, BM=128 BN=64.
// A staging: 2 threads/row (halves of 64 cols); ss via shfl_xor(1); two-pass
// (ss then scale+cvt) to keep VGPRs low. Frag layouts identical to bgemm_k.
// ---------------------------------------------------------------------------
__global__ __launch_bounds__(256) void bgemm_rms_k(
    const float* __restrict__ A, const float* __restrict__ w,
    const u16* __restrict__ Wt, float* __restrict__ C, int M, int N) {
  constexpr int BM = 128, BN = 64, K = 128;
  constexpr int LDT = K + 8;  // 136 u16 (272 B row stride; 16B-aligned)
  __shared__ u16 Al[BM][LDT];
  __shared__ u16 Wl[BN][LDT];
  int tid = threadIdx.x;
  int wid = tid >> 6, lane = tid & 63;
  int lrow = lane & 15, kh = lane >> 4;
  int bm = blockIdx.x * BM, bn = blockIdx.y * BN;

  // ---- A staging + fused RMS ----
  {
    int r = tid >> 1, hf = tid & 1;
    const float* ap = A + (size_t)(bm + r) * K + hf * 64;
    float ss = 0.f;
#pragma unroll
    for (int q = 0; q < 16; ++q) {
      float4 v = *(const float4*)(ap + q * 4);
      ss += v.x * v.x + v.y * v.y + v.z * v.z + v.w * v.w;
    }
    ss += __shfl_xor(ss, 1);  // partner thread holds the other 64 cols
    float rs = rsqrtf(ss * (1.f / Dd) + 1e-6f);
    const float* wp = w + hf * 64;
#pragma unroll
    for (int q = 0; q < 8; ++q) {  // 8 floats -> 8 bf16 -> one uint4 each
      float4 v0 = *(const float4*)(ap + q * 8);
      float4 v1 = *(const float4*)(ap + q * 8 + 4);
      float4 w0 = *(const float4*)(wp + q * 8);
      float4 w1 = *(const float4*)(wp + q * 8 + 4);
      uint4 u;
      u.x = pack2bf(v0.x * w0.x * rs, v0.y * w0.y * rs);
      u.y = pack2bf(v0.z * w0.z * rs, v0.w * w0.w * rs);
      u.z = pack2bf(v1.x * w1.x * rs, v1.y * w1.y * rs);
      u.w = pack2bf(v1.z * w1.z * rs, v1.w * w1.w * rs);
      *(uint4*)&Al[r][hf * 64 + q * 8] = u;
    }
  }
  // ---- W staging: 64 rows x 128 u16 = 1024 uint4 / 256 thr = 4 each ----
  {
    int n = tid >> 2, q = tid & 3;
    const uint4* wp = (const uint4*)(Wt + (size_t)(bn + n) * K + q * 32);
#pragma unroll
    for (int i = 0; i < 4; ++i)
      *(uint4*)&Wl[n][q * 32 + i * 8] = wp[i];
  }
  __syncthreads();

  f32x4 acc[2][4];
#pragma unroll
  for (int i = 0; i < 2; ++i)
#pragma unroll
    for (int j = 0; j < 4; ++j) acc[i][j] = (f32x4){0.f, 0.f, 0.f, 0.f};

#pragma unroll
  for (int ks = 0; ks < 4; ++ks) {
    short8b afr[2], wfr[4];
#pragma unroll
    for (int i = 0; i < 2; ++i)
      afr[i] = *(const short8b*)&Al[wid * 32 + i * 16 + lrow][ks * 32 + kh * 8];
#pragma unroll
    for (int j = 0; j < 4; ++j)
      wfr[j] = *(const short8b*)&Wl[j * 16 + lrow][ks * 32 + kh * 8];
#pragma unroll
    for (int i = 0; i < 2; ++i)
#pragma unroll
      for (int j = 0; j < 4; ++j)
        acc[i][j] = __builtin_amdgcn_mfma_f32_16x16x32_bf16(
            afr[i], wfr[j], acc[i][j], 0, 0, 0);
  }

#pragma unroll
  for (int i = 0; i < 2; ++i)
#pragma unroll
    for (int j = 0; j < 4; ++j)
#pragma unroll
      for (int rg = 0; rg < 4; ++rg) {
        int row = bm + wid * 32 + i * 16 + kh * 4 + rg;
        int col = bn + j * 16 + lrow;
        C[(size_t)row * N + col] = acc[i][j][rg];
      }
}

// ---------------------------------------------------------------------------
// bgemm_k: bf16-MFMA GEMM (validated round 12). C = A(f32,cvt) @ Wt[N][K].
// ---------------------------------------------------------------------------
template <bool ADD_C>
__global__ __launch_bounds__(256) void bgemm_k(
    const float* __restrict__ A, const u16* __restrict__ Wt,
    float* __restrict__ C, int M, int N, int K) {
  constexpr int BM = 128, BN = 64, BK = 32;
  constexpr int LDT = BK + 8;
  __shared__ u16 Al[BM][LDT];
  __shared__ u16 Wl[BN][LDT];
  int tid = threadIdx.x;
  int wid = tid >> 6, lane = tid & 63;
  int lrow = lane & 15, kh = lane >> 4;
  int bm = blockIdx.x * BM, bn = blockIdx.y * BN;

  f32x4 acc[2][4];
#pragma unroll
  for (int i = 0; i < 2; ++i)
#pragma unroll
    for (int j = 0; j < 4; ++j) acc[i][j] = (f32x4){0.f, 0.f, 0.f, 0.f};

  for (int k0 = 0; k0 < K; k0 += BK) {
    {
      int r = tid >> 1, hf = tid & 1;
      const float* ap = A + (size_t)(bm + r) * K + k0 + hf * 16;
      float4 a0 = *(const float4*)(ap + 0);
      float4 a1 = *(const float4*)(ap + 4);
      float4 a2 = *(const float4*)(ap + 8);
      float4 a3 = *(const float4*)(ap + 12);
      uint4 w0, w1;
      w0.x = pack2bf(a0.x, a0.y); w0.y = pack2bf(a0.z, a0.w);
      w0.z = pack2bf(a1.x, a1.y); w0.w = pack2bf(a1.z, a1.w);
      w1.x = pack2bf(a2.x, a2.y); w1.y = pack2bf(a2.z, a2.w);
      w1.z = pack2bf(a3.x, a3.y); w1.w = pack2bf(a3.z, a3.w);
      *(uint4*)&Al[r][hf * 16]     = w0;
      *(uint4*)&Al[r][hf * 16 + 8] = w1;
    }
    if (tid < 128) {
      int n = tid >> 1, hf = tid & 1;
      const uint4* wp = (const uint4*)(Wt + (size_t)(bn + n) * K + k0 + hf * 16);
      uint4 v0 = wp[0], v1 = wp[1];
      *(uint4*)&Wl[n][hf * 16]     = v0;
      *(uint4*)&Wl[n][hf * 16 + 8] = v1;
    }
    __syncthreads();

    short8b afr[2], wfr[4];
#pragma unroll
    for (int i = 0; i < 2; ++i)
      afr[i] = *(const short8b*)&Al[wid * 32 + i * 16 + lrow][kh * 8];
#pragma unroll
    for (int j = 0; j < 4; ++j)
      wfr[j] = *(const short8b*)&Wl[j * 16 + lrow][kh * 8];
#pragma unroll
    for (int i = 0; i < 2; ++i)
#pragma unroll
      for (int j = 0; j < 4; ++j)
        acc[i][j] = __builtin_amdgcn_mfma_f32_16x16x32_bf16(
            afr[i], wfr[j], acc[i][j], 0, 0, 0);
    __syncthreads();
  }

#pragma unroll
  for (int i = 0; i < 2; ++i)
#pragma unroll
    for (int j = 0; j < 4; ++j)
#pragma unroll
      for (int rg = 0; rg < 4; ++rg) {
        int row = bm + wid * 32 + i * 16 + kh * 4 + rg;
        int col = bn + j * 16 + lrow;
        size_t off = (size_t)row * N + col;
        C[off] = acc[i][j][rg] + (ADD_C ? C[off] : 0.f);
      }
}

// ---------------------------------------------------------------------------
// convdw4_k: depthwise causal conv (k=4) + SiLU, float4-vectorized over di.
// Thread handles 4 consecutive di for one (b,t). grid ROWS*64/256.
// ---------------------------------------------------------------------------
__global__ __launch_bounds__(256) void convdw4_k(const float* __restrict__ xz,
                                                 const float* __restrict__ cw,
                                                 const float* __restrict__ cb,
                                                 float* __restrict__ xc) {
  int idx = blockIdx.x * 256 + threadIdx.x;  // bt*64 + di_quad
  int di4 = (idx & 63) * 4;
  int bt  = idx >> 6;
  int t   = bt & (Tt - 1);
  float4 w0 = *(const float4*)&cw[(di4 + 0) * DC];
  float4 w1 = *(const float4*)&cw[(di4 + 1) * DC];
  float4 w2 = *(const float4*)&cw[(di4 + 2) * DC];
  float4 w3 = *(const float4*)&cw[(di4 + 3) * DC];
  float4 a = *(const float4*)&cb[di4];
#pragma unroll
  for (int k = 0; k < DC; ++k) {
    int tt = t - (DC - 1) + k;
    if (tt >= 0) {
      float4 v = *(const float4*)&xz[(size_t)(bt - t + tt) * (2 * DI) + di4];
      a.x = fmaf(v.x, f4c(w0, k), a.x);
      a.y = fmaf(v.y, f4c(w1, k), a.y);
      a.z = fmaf(v.z, f4c(w2, k), a.z);
      a.w = fmaf(v.w, f4c(w3, k), a.w);
    }
  }
  float4 o;
  o.x = a.x / (1.f + expf(-a.x));
  o.y = a.y / (1.f + expf(-a.y));
  o.z = a.z / (1.f + expf(-a.z));
  o.w = a.w / (1.f + expf(-a.w));
  *(float4*)&xc[(size_t)bt * DI + di4] = o;
}

// ---------------------------------------------------------------------------
// trans_k: builds time-major scan operands (dt GEMM + softplus folded in).
// ---------------------------------------------------------------------------
__global__ __launch_bounds__(256) void trans_k(
    const float* __restrict__ xdbl, const float* __restrict__ xc,
    const float* __restrict__ Wdt, const float* __restrict__ bdt,
    float* __restrict__ dtT, float* __restrict__ uT, float* __restrict__ bcT) {
  __shared__ float t1[32][33];
  __shared__ float t2[32][33];
  __shared__ float dtl[32][9];
  __shared__ float wts[8][33];
  __shared__ float bts[32];
  int t0 = blockIdx.x * 32, b = blockIdx.z, y = blockIdx.y;
  int tid = threadIdx.x;
  int j = tid & 31, i0 = tid >> 5;
  if (y < 8) {
    int di0 = y * 32;
    {
      int r = tid >> 3, c = tid & 7;
      dtl[r][c] = xdbl[((size_t)b * Tt + t0 + r) * NX + c];
      wts[i0][j] = Wdt[i0 * DI + di0 + j];
      if (tid < 32) bts[tid] = bdt[di0 + tid];
    }
    __syncthreads();
#pragma unroll
    for (int ii = 0; ii < 4; ++ii) {
      int i = i0 + ii * 8;
      float sacc = bts[j];
#pragma unroll
      for (int r = 0; r < 8; ++r) sacc = fmaf(dtl[i][r], wts[r][j], sacc);
      float sp = fmaxf(sacc, 0.f) + log1pf(expf(-fabsf(sacc)));
      float xcv = xc[((size_t)b * Tt + t0 + i) * DI + di0 + j];
      t1[i][j] = sp;
      t2[i][j] = sp * xcv;
    }
    __syncthreads();
#pragma unroll
    for (int ii = 0; ii < 4; ++ii) {
      int i = i0 + ii * 8;
      dtT[((size_t)b * DI + di0 + i) * Tt + t0 + j] = t1[j][i];
      uT [((size_t)b * DI + di0 + i) * Tt + t0 + j] = t2[j][i];
    }
  } else {
    int k0 = (y - 8) * 32;
#pragma unroll
    for (int ii = 0; ii < 4; ++ii) {
      int i = i0 + ii * 8;
      t1[i][j] = xdbl[((size_t)b * Tt + t0 + i) * NX + 8 + k0 + j];
    }
    __syncthreads();
#pragma unroll
    for (int ii = 0; ii < 4; ++ii) {
      int i = i0 + ii * 8;
      bcT[((size_t)b * 64 + k0 + i) * Tt + t0 + j] = t1[j][i];
    }
  }
}

// ---------------------------------------------------------------------------
// scan2_k: single-pass time-major scan, float4 chunked loads, 16-step double
// buffer, DPP reduce; pv buffered per 16 steps (one predicated store region).
// ---------------------------------------------------------------------------
__global__ __launch_bounds__(256) void scan2_k(
    const float* __restrict__ dtT, const float* __restrict__ uT,
    const float* __restrict__ bcT, const float* __restrict__ A_log,
    const float* __restrict__ alpha, const float* __restrict__ beta,
    float* __restrict__ pT, int layer) {
  int b = blockIdx.y;
  int hw = threadIdx.x >> 5, s = threadIdx.x & 31;
  int di = blockIdx.x * 8 + hw;
  float a = alpha[layer], bc = beta[layer], ab = a * bc;
  float Al2 = -expf(A_log[di * DS + s]) * 1.4426950408889634f;
  const float* dp = dtT + ((size_t)b * DI + di) * Tt;
  const float* up = uT  + ((size_t)b * DI + di) * Tt;
  const float* Bp = bcT + ((size_t)b * 64 + s) * Tt;
  const float* Cp = bcT + ((size_t)b * 64 + 32 + s) * Tt;
  float* pp = pT + ((size_t)b * DI + di) * Tt;

  float h = 0.f, v = 0.f;
  float4 dA_[4], uA_[4], BA_[4], CA_[4];
  float4 dB_[4], uB_[4], BB_[4], CB_[4];

  auto LOAD = [&](float4* d4, float4* u4, float4* B4, float4* C4, int c) {
    int t0 = c * 16;
#pragma unroll
    for (int q = 0; q < 4; ++q) {
      d4[q] = *(const float4*)(dp + t0 + q * 4);
      u4[q] = *(const float4*)(up + t0 + q * 4);
      B4[q] = *(const float4*)(Bp + t0 + q * 4);
      C4[q] = *(const float4*)(Cp + t0 + q * 4);
    }
  };
  auto COMP = [&](const float4* d4, const float4* u4, const float4* B4,
                  const float4* C4, int c) {
    int t0 = c * 16;
    float pvs[16];
#pragma unroll
    for (int kk = 0; kk < 16; ++kk) {
      float dA  = exp2f(f4c(d4[kk >> 2], kk & 3) * Al2);
      float dBx = f4c(u4[kk >> 2], kk & 3) * f4c(B4[kk >> 2], kk & 3);
      float u2  = fmaf(ab, v, dBx);     // uses v_{t-1}
      h = fmaf(dA, h, u2);
      v = fmaf(bc, v, dBx);
      pvs[kk] = half_wave_sum31(h * f4c(C4[kk >> 2], kk & 3));
    }
    if (s == 31) {
#pragma unroll
      for (int q = 0; q < 4; ++q) {
        float4 pv = {pvs[q * 4], pvs[q * 4 + 1], pvs[q * 4 + 2], pvs[q * 4 + 3]};
        *(float4*)(pp + t0 + q * 4) = pv;
      }
    }
  };

  constexpr int NC = Tt / 16;  // 64, even
  LOAD(dA_, uA_, BA_, CA_, 0);
  for (int c = 0; c < NC; c += 2) {
    LOAD(dB_, uB_, BB_, CB_, c + 1);
    COMP(dA_, uA_, BA_, CA_, c);
    LOAD(dA_, uA_, BA_, CA_, (c + 2 < NC) ? c + 2 : NC - 1);
    COMP(dB_, uB_, BB_, CB_, c + 1);
  }
}

// ---------------------------------------------------------------------------
// gate_k: transpose pT back to row-major, apply y = (p + D*xc)*silu(z).
// ---------------------------------------------------------------------------
__global__ __launch_bounds__(256) void gate_k(
    const float* __restrict__ pT, const float* __restrict__ xc,
    const float* __restrict__ xz, const float* __restrict__ Dp_,
    float* __restrict__ y) {
  __shared__ float tile[32][33];
  int t0 = blockIdx.x * 32, di0 = blockIdx.y * 32, b = blockIdx.z;
  int j = threadIdx.x & 31, i0 = threadIdx.x >> 5;
#pragma unroll
  for (int ii = 0; ii < 4; ++ii) {
    int r = i0 + ii * 8;
    tile[r][j] = pT[((size_t)b * DI + di0 + r) * Tt + t0 + j];
  }
  __syncthreads();
#pragma unroll
  for (int ii = 0; ii < 4; ++ii) {
    int i = i0 + ii * 8;  // t offset
    size_t row = (size_t)b * Tt + t0 + i;
    float p   = tile[j][i];
    float xcv = xc[row * DI + di0 + j];
    float zz  = xz[row * (2 * DI) + DI + di0 + j];
    float g   = zz / (1.f + expf(-zz));
    y[row * DI + di0 + j] = fmaf(Dp_[di0 + j], xcv, p) * g;
  }
}

// ---------------------------------------------------------------------------
extern "C" void kernel_launch(void* const* d_in, const int* in_sizes, int n_in,
                              void* d_out, int out_size, void* d_ws, size_t ws_size,
                              hipStream_t stream) {
  const float* x       = (const float*)d_in[0];
  const float* conv_fw = (const float*)d_in[1];
  const float* conv_fb = (const float*)d_in[2];
  const float* bn_g    = (const float*)d_in[3];
  const float* bn_b    = (const float*)d_in[4];
  const float* rms_w   = (const float*)d_in[5];
  const float* W_in    = (const float*)d_in[6];
  const float* conv_w  = (const float*)d_in[7];
  const float* conv_b  = (const float*)d_in[8];
  const float* W_xp    = (const float*)d_in[9];
  const float* W_dt    = (const float*)d_in[10];
  const float* b_dt    = (const float*)d_in[11];
  const float* A_log   = (const float*)d_in[12];
  const float* D_par   = (const float*)d_in[13];
  const float* W_out   = (const float*)d_in[14];
  const float* alpha   = (const float*)d_in[15];
  const float* beta    = (const float*)d_in[16];
  const float* norm_w  = (const float*)d_in[17];
  float* out = (float*)d_out;

  // Workspace (floats); every buffer written before read each launch.
  float* ws   = (float*)d_ws;
  float* h    = ws;                    // 1,048,576
  float* xz   = h + 1048576;           // 4,194,304
  float* xc   = xz + 4194304;          // 2,097,152
  float* xdbl = xc + 2097152;          // 589,824
  float* pT   = xdbl + 589824;         // 2,097,152
  float* uT   = pT + 2097152;          // 2,097,152
  float* bcT  = uT + 2097152;          // 524,288
  float* shrd = bcT + 524288;          // 2,097,152 (dtT / ytot, disjoint lifetimes)
  u16*  wt_in  = (u16*)(shrd + 2097152);       // 2 x 512 x 128 u16
  u16*  wt_out = wt_in + 2 * (2 * DI) * Dd;    // 2 x 128 x 256 u16
  float* dtT  = shrd;
  float* ytot = shrd;

  // Weight transpose+cast, both layers batched via grid.z.
  wtrans_k<<<dim3(Dd / 32, (2 * DI) / 32, Ll), 256, 0, stream>>>(
      W_in, wt_in, Dd, 2 * DI);
  wtrans_k<<<dim3(DI / 32, Dd / 32, Ll), 256, 0, stream>>>(
      W_out, wt_out, DI, Dd);

  frontend_k<<<dim3(Tt, Bb), 128, 0, stream>>>(x, conv_fw, conv_fb, bn_g, bn_b, h);

  for (int l = 0; l < Ll; ++l) {
    bgemm_rms_k<<<dim3(ROWS / 128, (2 * DI) / 64), 256, 0, stream>>>(
        h, rms_w + l * Dd, wt_in + (size_t)l * (2 * DI) * Dd, xz, ROWS, 2 * DI);
    convdw4_k<<<(ROWS * (DI / 4)) / 256, 256, 0, stream>>>(
        xz, conv_w + l * DI * DC, conv_b + l * DI, xc);
    sgemm_k<false><<<dim3(ROWS / 128, (NX + 63) / 64), 256, 0, stream>>>(
        xc, W_xp + (size_t)l * DI * NX, xdbl, ROWS, NX, DI);
    trans_k<<<dim3(Tt / 32, 10, Bb), 256, 0, stream>>>(
        xdbl, xc, W_dt + l * DTR * DI, b_dt + l * DI, dtT, uT, bcT);
    scan2_k<<<dim3(DI / 8, Bb), 256, 0, stream>>>(
        dtT, uT, bcT, A_log + l * DI * DS, alpha, beta, pT, l);
    gate_k<<<dim3(Tt / 32, DI / 32, Bb), 256, 0, stream>>>(
        pT, xc, xz, D_par + l * DI, ytot);
    bgemm_k<true><<<dim3(ROWS / 128, Dd / 64), 256, 0, stream>>>(
        ytot, wt_out + (size_t)l * Dd * DI, h, ROWS, Dd, DI);
  }

  rms_k<<<ROWS / 4, 256, 0, stream>>>(h, norm_w, out);
}

// Round 15
// 403.272 us; speedup vs baseline: 1.2041x; 1.2041x over previous
//
#include <hip/hip_runtime.h>
#include <hip/hip_bf16.h>
#include <math.h>

// Problem constants (from reference)
constexpr int Bb  = 8;
constexpr int Tt  = 1024;
constexpr int CIN = 6;
constexpr int Dd  = 128;
constexpr int Ll  = 2;
constexpr int DI  = 256;
constexpr int DS  = 32;
constexpr int DC  = 4;
constexpr int DTR = 8;
constexpr int NX  = DTR + 2 * DS;   // 72
constexpr int NXP = 128;            // padded NX for MFMA
constexpr int ROWS = Bb * Tt;       // 8192

using u16 = unsigned short;
using u32 = unsigned int;

typedef __attribute__((ext_vector_type(8))) short short8b;  // 8 bf16 (4 VGPR)
typedef __attribute__((ext_vector_type(4))) float f32x4;

__device__ __forceinline__ float f4c(const float4& v, int k) {
  return k == 0 ? v.x : k == 1 ? v.y : k == 2 ? v.z : v.w;
}

// f32 -> bf16 (RNE), raw bits
__device__ __forceinline__ u16 f2bf(float f) {
  u32 x = __float_as_uint(f);
  u32 r = (x + 0x7fffu + ((x >> 16) & 1u)) >> 16;
  return (u16)r;
}
__device__ __forceinline__ u32 pack2bf(float lo, float hi) {
  return (u32)f2bf(lo) | ((u32)f2bf(hi) << 16);
}

// VALU (DPP) lane-sum stage: x + dpp_move(x). Avoids the DS pipe entirely.
template <int CTRL, int ROW_MASK>
__device__ __forceinline__ float dpp_add(float x) {
  int m = __builtin_amdgcn_update_dpp(0, __float_as_int(x), CTRL, ROW_MASK, 0xF, true);
  return x + __int_as_float(m);
}
// Sum of 32 lanes within each 32-lane half-wave; result in lane s==31 (and 63).
__device__ __forceinline__ float half_wave_sum31(float p) {
  p = dpp_add<0x111, 0xF>(p);
  p = dpp_add<0x112, 0xF>(p);
  p = dpp_add<0x114, 0xF>(p);
  p = dpp_add<0x118, 0xF>(p);
  p = dpp_add<0x142, 0xA>(p);
  return p;
}

// ---------------------------------------------------------------------------
// Frontend: Conv1d(CIN->D, k=3, pad=1) + BN(eval) + ReLU
// ---------------------------------------------------------------------------
__global__ __launch_bounds__(128) void frontend_k(
    const float* __restrict__ x, const float* __restrict__ fw,
    const float* __restrict__ fb, const float* __restrict__ g,
    const float* __restrict__ bnb, float* __restrict__ h) {
  int t = blockIdx.x, b = blockIdx.y, d = threadIdx.x;
  float acc = 0.f;
#pragma unroll
  for (int k = 0; k < 3; ++k) {
    int tt = t - 1 + k;
    if (tt < 0 || tt >= Tt) continue;
    const float* xp = x + ((size_t)b * Tt + tt) * CIN;
#pragma unroll
    for (int c = 0; c < CIN; ++c)
      acc = fmaf(xp[c], fw[(d * CIN + c) * 3 + k], acc);
  }
  float scale = g[d] * rsqrtf(1.f + 1e-5f);
  float val = scale * (acc + fb[d]) + bnb[d];
  h[((size_t)b * Tt + t) * Dd + d] = fmaxf(val, 0.f);
}

// ---------------------------------------------------------------------------
// RMSNorm (final only). One wave per row; 4 rows/block.
// ---------------------------------------------------------------------------
__global__ __launch_bounds__(256) void rms_k(const float* __restrict__ in,
                                             const float* __restrict__ w,
                                             float* __restrict__ out) {
  int lane = threadIdx.x & 63;
  int row  = blockIdx.x * 4 + (threadIdx.x >> 6);
  const float* p = in + (size_t)row * Dd;
  float x0 = p[lane], x1 = p[lane + 64];
  float ss = fmaf(x0, x0, x1 * x1);
#pragma unroll
  for (int m = 1; m < 64; m <<= 1) ss += __shfl_xor(ss, m);
  float rs = rsqrtf(ss * (1.f / Dd) + 1e-6f);
  out[(size_t)row * Dd + lane]      = x0 * w[lane] * rs;
  out[(size_t)row * Dd + lane + 64] = x1 * w[lane + 64] * rs;
}

// ---------------------------------------------------------------------------
// wtrans_k: W[K][N] f32 -> Wt[N][K] bf16 (transpose + cast), 32x32 LDS tiles.
// grid (K/32, N/32, L); layer stride = K*N on both.
// ---------------------------------------------------------------------------
__global__ __launch_bounds__(256) void wtrans_k(const float* __restrict__ W,
                                                u16* __restrict__ Wt,
                                                int K, int N) {
  __shared__ float tile[32][33];
  int k0 = blockIdx.x * 32, n0 = blockIdx.y * 32;
  size_t lofs = (size_t)blockIdx.z * K * N;
  const float* Wp = W + lofs;
  u16* Wtp = Wt + lofs;
  int j = threadIdx.x & 31, i0 = threadIdx.x >> 5;
#pragma unroll
  for (int ii = 0; ii < 4; ++ii) {
    int k = i0 + ii * 8;
    tile[k][j] = Wp[(size_t)(k0 + k) * N + n0 + j];
  }
  __syncthreads();
  int kp = (threadIdx.x & 15) * 2;
  int nb = threadIdx.x >> 4;  // 0..15
#pragma unroll
  for (int half = 0; half < 2; ++half) {
    int n = nb + half * 16;
    u32 u = (u32)f2bf(tile[kp][n]) | ((u32)f2bf(tile[kp + 1][n]) << 16);
    *(u32*)&Wtp[(size_t)(n0 + n) * K + k0 + kp] = u;
  }
}

// ---------------------------------------------------------------------------
// wtransxp_k: W_xp[K=256][N=72] f32 -> Wt[NXP=128][256] bf16, zero-padded
// rows n>=72. grid (256/32, 128/32, Ll).
// ---------------------------------------------------------------------------
__global__ __launch_bounds__(256) void wtransxp_k(const float* __restrict__ W,
                                                  u16* __restrict__ Wt) {
  __shared__ float tile[32][33];
  int k0 = blockIdx.x * 32, n0 = blockIdx.y * 32;
  const float* Wp = W + (size_t)blockIdx.z * DI * NX;
  u16* Wtp = Wt + (size_t)blockIdx.z * NXP * DI;
  int j = threadIdx.x & 31, i0 = threadIdx.x >> 5;
#pragma unroll
  for (int ii = 0; ii < 4; ++ii) {
    int k = i0 + ii * 8;
    int n = n0 + j;
    tile[k][j] = (n < NX) ? Wp[(size_t)(k0 + k) * NX + n] : 0.f;
  }
  __syncthreads();
  int kp = (threadIdx.x & 15) * 2;
  int nb = threadIdx.x >> 4;
#pragma unroll
  for (int half = 0; half < 2; ++half) {
    int n = nb + half * 16;
    u32 u = (u32)f2bf(tile[kp][n]) | ((u32)f2bf(tile[kp + 1][n]) << 16);
    *(u32*)&Wtp[(size_t)(n0 + n) * DI + k0 + kp] = u;
  }
}

// ---------------------------------------------------------------------------
// bgemm_rms_k: fused RMSNorm + bf16-MFMA GEMM for W_in (validated round 13).
// ---------------------------------------------------------------------------
__global__ __launch_bounds__(256) void bgemm_rms_k(
    const float* __restrict__ A, const float* __restrict__ w,
    const u16* __restrict__ Wt, float* __restrict__ C, int M, int N) {
  constexpr int BM = 128, BN = 64, K = 128;
  constexpr int LDT = K + 8;
  __shared__ u16 Al[BM][LDT];
  __shared__ u16 Wl[BN][LDT];
  int tid = threadIdx.x;
  int wid = tid >> 6, lane = tid & 63;
  int lrow = lane & 15, kh = lane >> 4;
  int bm = blockIdx.x * BM, bn = blockIdx.y * BN;

  {
    int r = tid >> 1, hf = tid & 1;
    const float* ap = A + (size_t)(bm + r) * K + hf * 64;
    float ss = 0.f;
#pragma unroll
    for (int q = 0; q < 16; ++q) {
      float4 v = *(const float4*)(ap + q * 4);
      ss += v.x * v.x + v.y * v.y + v.z * v.z + v.w * v.w;
    }
    ss += __shfl_xor(ss, 1);
    float rs = rsqrtf(ss * (1.f / Dd) + 1e-6f);
    const float* wp = w + hf * 64;
#pragma unroll
    for (int q = 0; q < 8; ++q) {
      float4 v0 = *(const float4*)(ap + q * 8);
      float4 v1 = *(const float4*)(ap + q * 8 + 4);
      float4 w0 = *(const float4*)(wp + q * 8);
      float4 w1 = *(const float4*)(wp + q * 8 + 4);
      uint4 u;
      u.x = pack2bf(v0.x * w0.x * rs, v0.y * w0.y * rs);
      u.y = pack2bf(v0.z * w0.z * rs, v0.w * w0.w * rs);
      u.z = pack2bf(v1.x * w1.x * rs, v1.y * w1.y * rs);
      u.w = pack2bf(v1.z * w1.z * rs, v1.w * w1.w * rs);
      *(uint4*)&Al[r][hf * 64 + q * 8] = u;
    }
  }
  {
    int n = tid >> 2, q = tid & 3;
    const uint4* wp = (const uint4*)(Wt + (size_t)(bn + n) * K + q * 32);
#pragma unroll
    for (int i = 0; i < 4; ++i)
      *(uint4*)&Wl[n][q * 32 + i * 8] = wp[i];
  }
  __syncthreads();

  f32x4 acc[2][4];
#pragma unroll
  for (int i = 0; i < 2; ++i)
#pragma unroll
    for (int j = 0; j < 4; ++j) acc[i][j] = (f32x4){0.f, 0.f, 0.f, 0.f};

#pragma unroll
  for (int ks = 0; ks < 4; ++ks) {
    short8b afr[2], wfr[4];
#pragma unroll
    for (int i = 0; i < 2; ++i)
      afr[i] = *(const short8b*)&Al[wid * 32 + i * 16 + lrow][ks * 32 + kh * 8];
#pragma unroll
    for (int j = 0; j < 4; ++j)
      wfr[j] = *(const short8b*)&Wl[j * 16 + lrow][ks * 32 + kh * 8];
#pragma unroll
    for (int i = 0; i < 2; ++i)
#pragma unroll
      for (int j = 0; j < 4; ++j)
        acc[i][j] = __builtin_amdgcn_mfma_f32_16x16x32_bf16(
            afr[i], wfr[j], acc[i][j], 0, 0, 0);
  }

#pragma unroll
  for (int i = 0; i < 2; ++i)
#pragma unroll
    for (int j = 0; j < 4; ++j)
#pragma unroll
      for (int rg = 0; rg < 4; ++rg) {
        int row = bm + wid * 32 + i * 16 + kh * 4 + rg;
        int col = bn + j * 16 + lrow;
        C[(size_t)row * N + col] = acc[i][j][rg];
      }
}

// ---------------------------------------------------------------------------
// bgemm_k: bf16-MFMA GEMM (validated round 12). C = A(f32,cvt) @ Wt[N][K].
// ---------------------------------------------------------------------------
template <bool ADD_C>
__global__ __launch_bounds__(256) void bgemm_k(
    const float* __restrict__ A, const u16* __restrict__ Wt,
    float* __restrict__ C, int M, int N, int K) {
  constexpr int BM = 128, BN = 64, BK = 32;
  constexpr int LDT = BK + 8;
  __shared__ u16 Al[BM][LDT];
  __shared__ u16 Wl[BN][LDT];
  int tid = threadIdx.x;
  int wid = tid >> 6, lane = tid & 63;
  int lrow = lane & 15, kh = lane >> 4;
  int bm = blockIdx.x * BM, bn = blockIdx.y * BN;

  f32x4 acc[2][4];
#pragma unroll
  for (int i = 0; i < 2; ++i)
#pragma unroll
    for (int j = 0; j < 4; ++j) acc[i][j] = (f32x4){0.f, 0.f, 0.f, 0.f};

  for (int k0 = 0; k0 < K; k0 += BK) {
    {
      int r = tid >> 1, hf = tid & 1;
      const float* ap = A + (size_t)(bm + r) * K + k0 + hf * 16;
      float4 a0 = *(const float4*)(ap + 0);
      float4 a1 = *(const float4*)(ap + 4);
      float4 a2 = *(const float4*)(ap + 8);
      float4 a3 = *(const float4*)(ap + 12);
      uint4 w0, w1;
      w0.x = pack2bf(a0.x, a0.y); w0.y = pack2bf(a0.z, a0.w);
      w0.z = pack2bf(a1.x, a1.y); w0.w = pack2bf(a1.z, a1.w);
      w1.x = pack2bf(a2.x, a2.y); w1.y = pack2bf(a2.z, a2.w);
      w1.z = pack2bf(a3.x, a3.y); w1.w = pack2bf(a3.z, a3.w);
      *(uint4*)&Al[r][hf * 16]     = w0;
      *(uint4*)&Al[r][hf * 16 + 8] = w1;
    }
    if (tid < 128) {
      int n = tid >> 1, hf = tid & 1;
      const uint4* wp = (const uint4*)(Wt + (size_t)(bn + n) * K + k0 + hf * 16);
      uint4 v0 = wp[0], v1 = wp[1];
      *(uint4*)&Wl[n][hf * 16]     = v0;
      *(uint4*)&Wl[n][hf * 16 + 8] = v1;
    }
    __syncthreads();

    short8b afr[2], wfr[4];
#pragma unroll
    for (int i = 0; i < 2; ++i)
      afr[i] = *(const short8b*)&Al[wid * 32 + i * 16 + lrow][kh * 8];
#pragma unroll
    for (int j = 0; j < 4; ++j)
      wfr[j] = *(const short8b*)&Wl[j * 16 + lrow][kh * 8];
#pragma unroll
    for (int i = 0; i < 2; ++i)
#pragma unroll
      for (int j = 0; j < 4; ++j)
        acc[i][j] = __builtin_amdgcn_mfma_f32_16x16x32_bf16(
            afr[i], wfr[j], acc[i][j], 0, 0, 0);
    __syncthreads();
  }

#pragma unroll
  for (int i = 0; i < 2; ++i)
#pragma unroll
    for (int j = 0; j < 4; ++j)
#pragma unroll
      for (int rg = 0; rg < 4; ++rg) {
        int row = bm + wid * 32 + i * 16 + kh * 4 + rg;
        int col = bn + j * 16 + lrow;
        size_t off = (size_t)row * N + col;
        C[off] = acc[i][j][rg] + (ADD_C ? C[off] : 0.f);
      }
}

// ---------------------------------------------------------------------------
// bgemm_xp_k: bf16-MFMA GEMM for W_xproj. Computes Npad=128 cols from padded
// Wt[128][256]; stores only cols < NX=72 at output stride NX. Same frag
// layout as bgemm_k. grid (ROWS/128, 2).
// ---------------------------------------------------------------------------
__global__ __launch_bounds__(256) void bgemm_xp_k(
    const float* __restrict__ A, const u16* __restrict__ Wt,
    float* __restrict__ C) {
  constexpr int BM = 128, BN = 64, BK = 32, K = DI;
  constexpr int LDT = BK + 8;
  __shared__ u16 Al[BM][LDT];
  __shared__ u16 Wl[BN][LDT];
  int tid = threadIdx.x;
  int wid = tid >> 6, lane = tid & 63;
  int lrow = lane & 15, kh = lane >> 4;
  int bm = blockIdx.x * BM, bn = blockIdx.y * BN;

  f32x4 acc[2][4];
#pragma unroll
  for (int i = 0; i < 2; ++i)
#pragma unroll
    for (int j = 0; j < 4; ++j) acc[i][j] = (f32x4){0.f, 0.f, 0.f, 0.f};

  for (int k0 = 0; k0 < K; k0 += BK) {
    {
      int r = tid >> 1, hf = tid & 1;
      const float* ap = A + (size_t)(bm + r) * K + k0 + hf * 16;
      float4 a0 = *(const float4*)(ap + 0);
      float4 a1 = *(const float4*)(ap + 4);
      float4 a2 = *(const float4*)(ap + 8);
      float4 a3 = *(const float4*)(ap + 12);
      uint4 w0, w1;
      w0.x = pack2bf(a0.x, a0.y); w0.y = pack2bf(a0.z, a0.w);
      w0.z = pack2bf(a1.x, a1.y); w0.w = pack2bf(a1.z, a1.w);
      w1.x = pack2bf(a2.x, a2.y); w1.y = pack2bf(a2.z, a2.w);
      w1.z = pack2bf(a3.x, a3.y); w1.w = pack2bf(a3.z, a3.w);
      *(uint4*)&Al[r][hf * 16]     = w0;
      *(uint4*)&Al[r][hf * 16 + 8] = w1;
    }
    if (tid < 128) {
      int n = tid >> 1, hf = tid & 1;
      const uint4* wp = (const uint4*)(Wt + (size_t)(bn + n) * K + k0 + hf * 16);
      uint4 v0 = wp[0], v1 = wp[1];
      *(uint4*)&Wl[n][hf * 16]     = v0;
      *(uint4*)&Wl[n][hf * 16 + 8] = v1;
    }
    __syncthreads();

    short8b afr[2], wfr[4];
#pragma unroll
    for (int i = 0; i < 2; ++i)
      afr[i] = *(const short8b*)&Al[wid * 32 + i * 16 + lrow][kh * 8];
#pragma unroll
    for (int j = 0; j < 4; ++j)
      wfr[j] = *(const short8b*)&Wl[j * 16 + lrow][kh * 8];
#pragma unroll
    for (int i = 0; i < 2; ++i)
#pragma unroll
      for (int j = 0; j < 4; ++j)
        acc[i][j] = __builtin_amdgcn_mfma_f32_16x16x32_bf16(
            afr[i], wfr[j], acc[i][j], 0, 0, 0);
    __syncthreads();
  }

#pragma unroll
  for (int i = 0; i < 2; ++i)
#pragma unroll
    for (int j = 0; j < 4; ++j)
#pragma unroll
      for (int rg = 0; rg < 4; ++rg) {
        int row = bm + wid * 32 + i * 16 + kh * 4 + rg;
        int col = bn + j * 16 + lrow;
        if (col < NX) C[(size_t)row * NX + col] = acc[i][j][rg];
      }
}

// ---------------------------------------------------------------------------
// convdw4_k: depthwise causal conv (k=4) + SiLU, float4-vectorized over di.
// ---------------------------------------------------------------------------
__global__ __launch_bounds__(256) void convdw4_k(const float* __restrict__ xz,
                                                 const float* __restrict__ cw,
                                                 const float* __restrict__ cb,
                                                 float* __restrict__ xc) {
  int idx = blockIdx.x * 256 + threadIdx.x;  // bt*64 + di_quad
  int di4 = (idx & 63) * 4;
  int bt  = idx >> 6;
  int t   = bt & (Tt - 1);
  float4 w0 = *(const float4*)&cw[(di4 + 0) * DC];
  float4 w1 = *(const float4*)&cw[(di4 + 1) * DC];
  float4 w2 = *(const float4*)&cw[(di4 + 2) * DC];
  float4 w3 = *(const float4*)&cw[(di4 + 3) * DC];
  float4 a = *(const float4*)&cb[di4];
#pragma unroll
  for (int k = 0; k < DC; ++k) {
    int tt = t - (DC - 1) + k;
    if (tt >= 0) {
      float4 v = *(const float4*)&xz[(size_t)(bt - t + tt) * (2 * DI) + di4];
      a.x = fmaf(v.x, f4c(w0, k), a.x);
      a.y = fmaf(v.y, f4c(w1, k), a.y);
      a.z = fmaf(v.z, f4c(w2, k), a.z);
      a.w = fmaf(v.w, f4c(w3, k), a.w);
    }
  }
  float4 o;
  o.x = a.x / (1.f + expf(-a.x));
  o.y = a.y / (1.f + expf(-a.y));
  o.z = a.z / (1.f + expf(-a.z));
  o.w = a.w / (1.f + expf(-a.w));
  *(float4*)&xc[(size_t)bt * DI + di4] = o;
}

// ---------------------------------------------------------------------------
// trans_k: builds time-major scan operands (dt GEMM + softplus folded in).
// ---------------------------------------------------------------------------
__global__ __launch_bounds__(256) void trans_k(
    const float* __restrict__ xdbl, const float* __restrict__ xc,
    const float* __restrict__ Wdt, const float* __restrict__ bdt,
    float* __restrict__ dtT, float* __restrict__ uT, float* __restrict__ bcT) {
  __shared__ float t1[32][33];
  __shared__ float t2[32][33];
  __shared__ float dtl[32][9];
  __shared__ float wts[8][33];
  __shared__ float bts[32];
  int t0 = blockIdx.x * 32, b = blockIdx.z, y = blockIdx.y;
  int tid = threadIdx.x;
  int j = tid & 31, i0 = tid >> 5;
  if (y < 8) {
    int di0 = y * 32;
    {
      int r = tid >> 3, c = tid & 7;
      dtl[r][c] = xdbl[((size_t)b * Tt + t0 + r) * NX + c];
      wts[i0][j] = Wdt[i0 * DI + di0 + j];
      if (tid < 32) bts[tid] = bdt[di0 + tid];
    }
    __syncthreads();
#pragma unroll
    for (int ii = 0; ii < 4; ++ii) {
      int i = i0 + ii * 8;
      float sacc = bts[j];
#pragma unroll
      for (int r = 0; r < 8; ++r) sacc = fmaf(dtl[i][r], wts[r][j], sacc);
      float sp = fmaxf(sacc, 0.f) + log1pf(expf(-fabsf(sacc)));
      float xcv = xc[((size_t)b * Tt + t0 + i) * DI + di0 + j];
      t1[i][j] = sp;
      t2[i][j] = sp * xcv;
    }
    __syncthreads();
#pragma unroll
    for (int ii = 0; ii < 4; ++ii) {
      int i = i0 + ii * 8;
      dtT[((size_t)b * DI + di0 + i) * Tt + t0 + j] = t1[j][i];
      uT [((size_t)b * DI + di0 + i) * Tt + t0 + j] = t2[j][i];
    }
  } else {
    int k0 = (y - 8) * 32;
#pragma unroll
    for (int ii = 0; ii < 4; ++ii) {
      int i = i0 + ii * 8;
      t1[i][j] = xdbl[((size_t)b * Tt + t0 + i) * NX + 8 + k0 + j];
    }
    __syncthreads();
#pragma unroll
    for (int ii = 0; ii < 4; ++ii) {
      int i = i0 + ii * 8;
      bcT[((size_t)b * 64 + k0 + i) * Tt + t0 + j] = t1[j][i];
    }
  }
}

// ---------------------------------------------------------------------------
// scan2_k: single-pass time-major scan [EXACT round-12 body: 82 us measured].
// float4 chunked loads, 16-step double buffer, DPP reduce, per-4-step store.
// ---------------------------------------------------------------------------
__global__ __launch_bounds__(256) void scan2_k(
    const float* __restrict__ dtT, const float* __restrict__ uT,
    const float* __restrict__ bcT, const float* __restrict__ A_log,
    const float* __restrict__ alpha, const float* __restrict__ beta,
    float* __restrict__ pT, int layer) {
  int b = blockIdx.y;
  int hw = threadIdx.x >> 5, s = threadIdx.x & 31;
  int di = blockIdx.x * 8 + hw;
  float a = alpha[layer], bc = beta[layer], ab = a * bc;
  float Al2 = -expf(A_log[di * DS + s]) * 1.4426950408889634f;
  const float* dp = dtT + ((size_t)b * DI + di) * Tt;
  const float* up = uT  + ((size_t)b * DI + di) * Tt;
  const float* Bp = bcT + ((size_t)b * 64 + s) * Tt;
  const float* Cp = bcT + ((size_t)b * 64 + 32 + s) * Tt;
  float* pp = pT + ((size_t)b * DI + di) * Tt;

  float h = 0.f, v = 0.f;
  float4 dA_[4], uA_[4], BA_[4], CA_[4];
  float4 dB_[4], uB_[4], BB_[4], CB_[4];

  auto LOAD = [&](float4* d4, float4* u4, float4* B4, float4* C4, int c) {
    int t0 = c * 16;
#pragma unroll
    for (int q = 0; q < 4; ++q) {
      d4[q] = *(const float4*)(dp + t0 + q * 4);
      u4[q] = *(const float4*)(up + t0 + q * 4);
      B4[q] = *(const float4*)(Bp + t0 + q * 4);
      C4[q] = *(const float4*)(Cp + t0 + q * 4);
    }
  };
  auto COMP = [&](const float4* d4, const float4* u4, const float4* B4,
                  const float4* C4, int c) {
    int t0 = c * 16;
    float4 pv;
#pragma unroll
    for (int kk = 0; kk < 16; ++kk) {
      float dA  = exp2f(f4c(d4[kk >> 2], kk & 3) * Al2);
      float dBx = f4c(u4[kk >> 2], kk & 3) * f4c(B4[kk >> 2], kk & 3);
      float u2  = fmaf(ab, v, dBx);     // uses v_{t-1}
      h = fmaf(dA, h, u2);
      v = fmaf(bc, v, dBx);
      float p = half_wave_sum31(h * f4c(C4[kk >> 2], kk & 3));
      if ((kk & 3) == 0) pv.x = p;
      else if ((kk & 3) == 1) pv.y = p;
      else if ((kk & 3) == 2) pv.z = p;
      else {
        pv.w = p;
        if (s == 31) *(float4*)(pp + t0 + (kk - 3)) = pv;
      }
    }
  };

  constexpr int NC = Tt / 16;  // 64, even
  LOAD(dA_, uA_, BA_, CA_, 0);
  for (int c = 0; c < NC; c += 2) {
    LOAD(dB_, uB_, BB_, CB_, c + 1);
    COMP(dA_, uA_, BA_, CA_, c);
    LOAD(dA_, uA_, BA_, CA_, (c + 2 < NC) ? c + 2 : NC - 1);
    COMP(dB_, uB_, BB_, CB_, c + 1);
  }
}

// ---------------------------------------------------------------------------
// gate_k: transpose pT back to row-major, apply y = (p + D*xc)*silu(z).
// ---------------------------------------------------------------------------
__global__ __launch_bounds__(256) void gate_k(
    const float* __restrict__ pT, const float* __restrict__ xc,
    const float* __restrict__ xz, const float* __restrict__ Dp_,
    float* __restrict__ y) {
  __shared__ float tile[32][33];
  int t0 = blockIdx.x * 32, di0 = blockIdx.y * 32, b = blockIdx.z;
  int j = threadIdx.x & 31, i0 = threadIdx.x >> 5;
#pragma unroll
  for (int ii = 0; ii < 4; ++ii) {
    int r = i0 + ii * 8;
    tile[r][j] = pT[((size_t)b * DI + di0 + r) * Tt + t0 + j];
  }
  __syncthreads();
#pragma unroll
  for (int ii = 0; ii < 4; ++ii) {
    int i = i0 + ii * 8;  // t offset
    size_t row = (size_t)b * Tt + t0 + i;
    float p   = tile[j][i];
    float xcv = xc[row * DI + di0 + j];
    float zz  = xz[row * (2 * DI) + DI + di0 + j];
    float g   = zz / (1.f + expf(-zz));
    y[row * DI + di0 + j] = fmaf(Dp_[di0 + j], xcv, p) * g;
  }
}

// ---------------------------------------------------------------------------
extern "C" void kernel_launch(void* const* d_in, const int* in_sizes, int n_in,
                              void* d_out, int out_size, void* d_ws, size_t ws_size,
                              hipStream_t stream) {
  const float* x       = (const float*)d_in[0];
  const float* conv_fw = (const float*)d_in[1];
  const float* conv_fb = (const float*)d_in[2];
  const float* bn_g    = (const float*)d_in[3];
  const float* bn_b    = (const float*)d_in[4];
  const float* rms_w   = (const float*)d_in[5];
  const float* W_in    = (const float*)d_in[6];
  const float* conv_w  = (const float*)d_in[7];
  const float* conv_b  = (const float*)d_in[8];
  const float* W_xp    = (const float*)d_in[9];
  const float* W_dt    = (const float*)d_in[10];
  const float* b_dt    = (const float*)d_in[11];
  const float* A_log   = (const float*)d_in[12];
  const float* D_par   = (const float*)d_in[13];
  const float* W_out   = (const float*)d_in[14];
  const float* alpha   = (const float*)d_in[15];
  const float* beta    = (const float*)d_in[16];
  const float* norm_w  = (const float*)d_in[17];
  float* out = (float*)d_out;

  // Workspace (floats); every buffer written before read each launch.
  float* ws   = (float*)d_ws;
  float* h    = ws;                    // 1,048,576
  float* xz   = h + 1048576;           // 4,194,304
  float* xc   = xz + 4194304;          // 2,097,152
  float* xdbl = xc + 2097152;          // 589,824
  float* pT   = xdbl + 589824;         // 2,097,152
  float* uT   = pT + 2097152;          // 2,097,152
  float* bcT  = uT + 2097152;          // 524,288
  float* shrd = bcT + 524288;          // 2,097,152 (dtT / ytot, disjoint lifetimes)
  u16*  wt_in  = (u16*)(shrd + 2097152);       // 2 x 512 x 128 u16
  u16*  wt_out = wt_in + 2 * (2 * DI) * Dd;    // 2 x 128 x 256 u16
  u16*  wt_xp  = wt_out + 2 * Dd * DI;         // 2 x 128 x 256 u16 (padded)
  float* dtT  = shrd;
  float* ytot = shrd;
  // total ~56.8 MiB (< 64.25 MiB proven budget)

  // Weight transpose+cast, layers batched via grid.z.
  wtrans_k<<<dim3(Dd / 32, (2 * DI) / 32, Ll), 256, 0, stream>>>(
      W_in, wt_in, Dd, 2 * DI);
  wtrans_k<<<dim3(DI / 32, Dd / 32, Ll), 256, 0, stream>>>(
      W_out, wt_out, DI, Dd);
  wtransxp_k<<<dim3(DI / 32, NXP / 32, Ll), 256, 0, stream>>>(W_xp, wt_xp);

  frontend_k<<<dim3(Tt, Bb), 128, 0, stream>>>(x, conv_fw, conv_fb, bn_g, bn_b, h);

  for (int l = 0; l < Ll; ++l) {
    bgemm_rms_k<<<dim3(ROWS / 128, (2 * DI) / 64), 256, 0, stream>>>(
        h, rms_w + l * Dd, wt_in + (size_t)l * (2 * DI) * Dd, xz, ROWS, 2 * DI);
    convdw4_k<<<(ROWS * (DI / 4)) / 256, 256, 0, stream>>>(
        xz, conv_w + l * DI * DC, conv_b + l * DI, xc);
    bgemm_xp_k<<<dim3(ROWS / 128, 2), 256, 0, stream>>>(
        xc, wt_xp + (size_t)l * NXP * DI, xdbl);
    trans_k<<<dim3(Tt / 32, 10, Bb), 256, 0, stream>>>(
        xdbl, xc, W_dt + l * DTR * DI, b_dt + l * DI, dtT, uT, bcT);
    scan2_k<<<dim3(DI / 8, Bb), 256, 0, stream>>>(
        dtT, uT, bcT, A_log + l * DI * DS, alpha, beta, pT, l);
    gate_k<<<dim3(Tt / 32, DI / 32, Bb), 256, 0, stream>>>(
        pT, xc, xz, D_par + l * DI, ytot);
    bgemm_k<true><<<dim3(ROWS / 128, Dd / 64), 256, 0, stream>>>(
        ytot, wt_out + (size_t)l * Dd * DI, h, ROWS, Dd, DI);
  }

  rms_k<<<ROWS / 4, 256, 0, stream>>>(h, norm_w, out);
}